// Round 6
// baseline (846.465 us; speedup 1.0000x reference)
//
#include <hip/hip_runtime.h>

#define IN_FEAT 512
#define HID 16
#define NC 7
#define NXCD 8

typedef int iv4 __attribute__((ext_vector_type(4)));  // native vector: nt-load OK

// ------------------------------------------------- degree histogram (int) ---
__global__ void k_count(const iv4* __restrict__ dst4, const int* __restrict__ dst,
                        int* __restrict__ deg, int E) {
    int j = blockIdx.x * blockDim.x + threadIdx.x;
    int E4 = E >> 2;
    if (j < E4) {
        iv4 d = __builtin_nontemporal_load(dst4 + j);
        atomicAdd(&deg[d.x], 1);
        atomicAdd(&deg[d.y], 1);
        atomicAdd(&deg[d.z], 1);
        atomicAdd(&deg[d.w], 1);
    }
    if (j == 0) {
        for (int e = E & ~3; e < E; ++e) atomicAdd(&deg[dst[e]], 1);
    }
}

// --------------------- 3-phase exclusive scan (+dinv fused into phase A) ----
__global__ __launch_bounds__(1024) void k_scanA(const int* __restrict__ deg,
                                                int* __restrict__ off,
                                                float* __restrict__ dinv,
                                                int* __restrict__ btot, int n) {
    __shared__ int wsum[16];
    int tid = threadIdx.x, lane = tid & 63, wid = tid >> 6;
    int i = blockIdx.x * 1024 + tid;
    int v = (i < n) ? deg[i] : 0;
    int incl = v;
#pragma unroll
    for (int o = 1; o < 64; o <<= 1) {
        int t = __shfl_up(incl, o, 64);
        if (lane >= o) incl += t;
    }
    if (lane == 63) wsum[wid] = incl;
    __syncthreads();
    int wpre = 0;
    for (int k = 0; k < wid; ++k) wpre += wsum[k];
    int ex = wpre + incl - v;
    if (i < n) {
        off[i] = ex;                         // local (no inter-block carry yet)
        dinv[i] = rsqrtf((float)v + 1.0f);   // +1 = self-loop
    }
    if (tid == 1023) btot[blockIdx.x] = ex + v;  // block total
}

__global__ __launch_bounds__(128) void k_scanB(const int* __restrict__ btot,
                                               int* __restrict__ bcar, int nb) {
    __shared__ int wsum[2];
    int tid = threadIdx.x, lane = tid & 63, wid = tid >> 6;
    int v = (tid < nb) ? btot[tid] : 0;
    int incl = v;
#pragma unroll
    for (int o = 1; o < 64; o <<= 1) {
        int t = __shfl_up(incl, o, 64);
        if (lane >= o) incl += t;
    }
    if (lane == 63) wsum[wid] = incl;
    __syncthreads();
    int wpre = (wid == 1) ? wsum[0] : 0;
    if (tid < nb) bcar[tid] = wpre + incl - v;
}

__global__ __launch_bounds__(1024) void k_scanC(int* __restrict__ off,
                                                const int* __restrict__ bcar,
                                                int* __restrict__ cur, int n, int E) {
    int i = blockIdx.x * 1024 + threadIdx.x;
    if (i < n) {
        int o = off[i] + bcar[blockIdx.x];
        off[i] = o;
        cur[i] = o;
    }
    if (i == 0) off[n] = E;
}

// -------------------------------- scatter src into CSR, XCD-affine ranges ---
// Block b: edge-chunk b>>3, dst-range b&7 (blocks round-robin across XCDs, so
// all writers of a CSR range share one L2). Batched iv4 loads give 8
// independent 16B loads in flight per thread (the R3/R4 version had VGPR=4:
// fully serialized, one 4B load at a time -> latency-bound).
__global__ void k_scatter(const iv4* __restrict__ src4, const iv4* __restrict__ dst4,
                          const int* __restrict__ src, const int* __restrict__ dst,
                          int* __restrict__ cur, int* __restrict__ csr_src,
                          int E, int n) {
    int chunk = blockIdx.x >> 3;
    int range = blockIdx.x & (NXCD - 1);
    int rsz = (n + NXCD - 1) / NXCD;
    int lo = range * rsz;
    int hi = min(n, lo + rsz);
    int E4 = E >> 2;
    int base = chunk * 1024 + threadIdx.x;  // iv4 index; 256 threads * 4 batches

    iv4 dv[4], sv[4];
    bool ok[4];
#pragma unroll
    for (int i = 0; i < 4; ++i) {
        int j = base + i * 256;
        ok[i] = (j < E4);
        if (ok[i]) {
            dv[i] = __builtin_nontemporal_load(dst4 + j);
            sv[i] = __builtin_nontemporal_load(src4 + j);
        }
    }
#pragma unroll
    for (int i = 0; i < 4; ++i) {
        if (!ok[i]) continue;
        iv4 d = dv[i], s = sv[i];
        if (d.x >= lo && d.x < hi) { int p = atomicAdd(&cur[d.x], 1); csr_src[p] = s.x; }
        if (d.y >= lo && d.y < hi) { int p = atomicAdd(&cur[d.y], 1); csr_src[p] = s.y; }
        if (d.z >= lo && d.z < hi) { int p = atomicAdd(&cur[d.z], 1); csr_src[p] = s.z; }
        if (d.w >= lo && d.w < hi) { int p = atomicAdd(&cur[d.w], 1); csr_src[p] = s.w; }
    }
    if (chunk == 0) {  // scalar tail (E % 4 edges)
        for (int e = (E & ~3) + (int)threadIdx.x; e < E; e += 256) {
            int d = dst[e];
            if (d >= lo && d < hi) { int p = atomicAdd(&cur[d], 1); csr_src[p] = src[e]; }
        }
    }
}

// ------------------------------------- layer 1: x @ W1 (4 lanes per row) ----
__global__ void k_gemm1(const float* __restrict__ x, const float* __restrict__ W,
                        float* __restrict__ h1, int n) {
    int t = blockIdx.x * blockDim.x + threadIdx.x;
    int row = t >> 2, part = t & 3;
    if (row >= n) return;
    const float4* xr = reinterpret_cast<const float4*>(x + (size_t)row * IN_FEAT) + part * 32;
    float acc[HID];
#pragma unroll
    for (int c = 0; c < HID; ++c) acc[c] = 0.0f;
#pragma unroll 4
    for (int kt = 0; kt < 32; ++kt) {
        float4 xv = xr[kt];
        const float* wk = W + ((size_t)part * 32 + kt) * 4 * HID;
#pragma unroll
        for (int c = 0; c < HID; ++c) acc[c] = fmaf(xv.x, wk[c], acc[c]);
#pragma unroll
        for (int c = 0; c < HID; ++c) acc[c] = fmaf(xv.y, wk[HID + c], acc[c]);
#pragma unroll
        for (int c = 0; c < HID; ++c) acc[c] = fmaf(xv.z, wk[2 * HID + c], acc[c]);
#pragma unroll
        for (int c = 0; c < HID; ++c) acc[c] = fmaf(xv.w, wk[3 * HID + c], acc[c]);
    }
    // combine the 4 partial K-slices across the 4-lane group
#pragma unroll
    for (int c = 0; c < HID; ++c) {
        acc[c] += __shfl_xor(acc[c], 1);
        acc[c] += __shfl_xor(acc[c], 2);
    }
    float4* hp = reinterpret_cast<float4*>(h1 + (size_t)row * HID);
    hp[part] = make_float4(acc[4 * part], acc[4 * part + 1], acc[4 * part + 2], acc[4 * part + 3]);
}

// ------------------- gather layer 1 + bias + relu + @W2 (fused, 4 lanes/v) --
__global__ void k_gather1(const float* __restrict__ h1, const int* __restrict__ csr_src,
                          const int* __restrict__ off, const float* __restrict__ dinv,
                          const float* __restrict__ b1, const float* __restrict__ W2,
                          float* __restrict__ h2, int n) {
    int t = blockIdx.x * blockDim.x + threadIdx.x;
    int v = t >> 2, part = t & 3;
    if (v >= n) return;
    float di = dinv[v];
    float4 hv = reinterpret_cast<const float4*>(h1 + (size_t)v * HID)[part];
    float dw = di * di;
    float4 acc = make_float4(hv.x * dw, hv.y * dw, hv.z * dw, hv.w * dw);
    int beg = off[v], end = off[v + 1];
    for (int i = beg; i < end; ++i) {
        int s = csr_src[i];  // cached: consecutive iters reuse the line
        float w = dinv[s] * di;
        float4 hs = reinterpret_cast<const float4*>(h1 + (size_t)s * HID)[part];
        acc.x = fmaf(hs.x, w, acc.x);
        acc.y = fmaf(hs.y, w, acc.y);
        acc.z = fmaf(hs.z, w, acc.z);
        acc.w = fmaf(hs.w, w, acc.w);
    }
    float tt[4];
    tt[0] = fmaxf(acc.x + b1[part * 4 + 0], 0.0f);
    tt[1] = fmaxf(acc.y + b1[part * 4 + 1], 0.0f);
    tt[2] = fmaxf(acc.z + b1[part * 4 + 2], 0.0f);
    tt[3] = fmaxf(acc.w + b1[part * 4 + 3], 0.0f);
    float o[NC];
#pragma unroll
    for (int c = 0; c < NC; ++c) o[c] = 0.0f;
#pragma unroll
    for (int j = 0; j < 4; ++j) {
        int k = part * 4 + j;
#pragma unroll
        for (int c = 0; c < NC; ++c) o[c] = fmaf(tt[j], W2[k * NC + c], o[c]);
    }
#pragma unroll
    for (int c = 0; c < NC; ++c) {
        o[c] += __shfl_xor(o[c], 1);
        o[c] += __shfl_xor(o[c], 2);
    }
    float4* hp = reinterpret_cast<float4*>(h2 + (size_t)v * 8);
    if (part == 0) hp[0] = make_float4(o[0], o[1], o[2], o[3]);
    if (part == 1) hp[1] = make_float4(o[4], o[5], o[6], 0.0f);
}

// ------------------- gather layer 2 + bias + log_softmax (fused, 1 th/v) ----
__global__ void k_gather2(const float* __restrict__ h2, const int* __restrict__ csr_src,
                          const int* __restrict__ off, const float* __restrict__ dinv,
                          const float* __restrict__ b2, float* __restrict__ out, int n) {
    int v = blockIdx.x * blockDim.x + threadIdx.x;
    if (v >= n) return;
    float di = dinv[v];
    float dw = di * di;
    const float4* hr = reinterpret_cast<const float4*>(h2 + (size_t)v * 8);
    float4 s0 = hr[0], s1 = hr[1];
    float4 a0 = make_float4(s0.x * dw, s0.y * dw, s0.z * dw, s0.w * dw);
    float4 a1 = make_float4(s1.x * dw, s1.y * dw, s1.z * dw, 0.0f);
    int beg = off[v], end = off[v + 1];
    for (int i = beg; i < end; ++i) {
        int s = csr_src[i];  // cached
        float w = dinv[s] * di;
        const float4* hs = reinterpret_cast<const float4*>(h2 + (size_t)s * 8);
        float4 v0 = hs[0], v1 = hs[1];
        a0.x = fmaf(v0.x, w, a0.x);
        a0.y = fmaf(v0.y, w, a0.y);
        a0.z = fmaf(v0.z, w, a0.z);
        a0.w = fmaf(v0.w, w, a0.w);
        a1.x = fmaf(v1.x, w, a1.x);
        a1.y = fmaf(v1.y, w, a1.y);
        a1.z = fmaf(v1.z, w, a1.z);
    }
    float z[NC];
    z[0] = a0.x + b2[0]; z[1] = a0.y + b2[1]; z[2] = a0.z + b2[2]; z[3] = a0.w + b2[3];
    z[4] = a1.x + b2[4]; z[5] = a1.y + b2[5]; z[6] = a1.z + b2[6];
    float m = z[0];
#pragma unroll
    for (int c = 1; c < NC; ++c) m = fmaxf(m, z[c]);
    float sum = 0.0f;
#pragma unroll
    for (int c = 0; c < NC; ++c) sum += expf(z[c] - m);
    float lse = logf(sum) + m;
#pragma unroll
    for (int c = 0; c < NC; ++c) out[(size_t)v * NC + c] = z[c] - lse;
}

// -----------------------------------------------------------------------------
extern "C" void kernel_launch(void* const* d_in, const int* in_sizes, int n_in,
                              void* d_out, int out_size, void* d_ws, size_t ws_size,
                              hipStream_t stream) {
    const float* x  = (const float*)d_in[0];
    const int*   ei = (const int*)d_in[1];
    const float* W1 = (const float*)d_in[2];
    const float* b1 = (const float*)d_in[3];
    const float* W2 = (const float*)d_in[4];
    const float* b2 = (const float*)d_in[5];

    int n = in_sizes[0] / IN_FEAT;
    int E = in_sizes[1] / 2;
    const int* src = ei;
    const int* dst = ei + E;
    const iv4* src4 = (const iv4*)src;
    const iv4* dst4 = (const iv4*)dst;

    // workspace layout (16B-aligned chunks first)
    char* p = (char*)d_ws;
    float* h1      = (float*)p;                 p += (size_t)HID * n * sizeof(float); // 6.4 MB
    float* h2      = (float*)p;                 p += (size_t)8 * n * sizeof(float);   // 3.2 MB
    int*   csr_src = (int*)p;                   p += (size_t)E * sizeof(int);         // 12.8 MB
    int*   deg     = (int*)p;                   p += (size_t)n * sizeof(int);
    int*   off     = (int*)p;                   p += (size_t)(n + 1) * sizeof(int);
    int*   cur     = (int*)p;                   p += (size_t)n * sizeof(int);
    float* dinv    = (float*)p;                 p += (size_t)n * sizeof(float);
    int*   btot    = (int*)p;                   p += (size_t)128 * sizeof(int);
    int*   bcar    = (int*)p;                   p += (size_t)128 * sizeof(int);

    const int tb = 256;
    int E4 = E >> 2;
    int gE4 = (E4 + tb - 1) / tb;
    int gN = (n + tb - 1) / tb;
    int gN4 = (4 * n + tb - 1) / tb;
    int nb = (n + 1023) / 1024;                       // scan blocks (<=128)
    int nchunk = (E4 + 1023) / 1024;                  // scatter chunks (4096 edges each)

    hipMemsetAsync(deg, 0, (size_t)n * sizeof(int), stream);
    k_count  <<<gE4, tb, 0, stream>>>(dst4, dst, deg, E);
    k_scanA  <<<nb, 1024, 0, stream>>>(deg, off, dinv, btot, n);
    k_scanB  <<<1, 128, 0, stream>>>(btot, bcar, nb);
    k_scanC  <<<nb, 1024, 0, stream>>>(off, bcar, cur, n, E);
    k_scatter<<<nchunk * NXCD, tb, 0, stream>>>(src4, dst4, src, dst, cur, csr_src, E, n);
    k_gemm1  <<<gN4, tb, 0, stream>>>(x, W1, h1, n);
    k_gather1<<<gN4, tb, 0, stream>>>(h1, csr_src, off, dinv, b1, W2, h2, n);
    k_gather2<<<gN,  tb, 0, stream>>>(h2, csr_src, off, dinv, b2, (float*)d_out, n);
}

// Round 7
// 482.873 us; speedup vs baseline: 1.7530x; 1.7530x over previous
//
#include <hip/hip_runtime.h>

#define IN_FEAT 512
#define HID 16
#define NC 7
#define NXCD 8

typedef int iv4 __attribute__((ext_vector_type(4)));  // native vector: nt-load OK

// ------------------------------------------------- degree histogram (int) ---
__global__ void k_count(const iv4* __restrict__ dst4, const int* __restrict__ dst,
                        int* __restrict__ deg, int E) {
    int j = blockIdx.x * blockDim.x + threadIdx.x;
    int E4 = E >> 2;
    if (j < E4) {
        iv4 d = __builtin_nontemporal_load(dst4 + j);
        atomicAdd(&deg[d.x], 1);
        atomicAdd(&deg[d.y], 1);
        atomicAdd(&deg[d.z], 1);
        atomicAdd(&deg[d.w], 1);
    }
    if (j == 0) {
        for (int e = E & ~3; e < E; ++e) atomicAdd(&deg[dst[e]], 1);
    }
}

// --------------------- 3-phase exclusive scan (+dinv fused into phase A) ----
__global__ __launch_bounds__(1024) void k_scanA(const int* __restrict__ deg,
                                                int* __restrict__ off,
                                                float* __restrict__ dinv,
                                                int* __restrict__ btot, int n) {
    __shared__ int wsum[16];
    int tid = threadIdx.x, lane = tid & 63, wid = tid >> 6;
    int i = blockIdx.x * 1024 + tid;
    int v = (i < n) ? deg[i] : 0;
    int incl = v;
#pragma unroll
    for (int o = 1; o < 64; o <<= 1) {
        int t = __shfl_up(incl, o, 64);
        if (lane >= o) incl += t;
    }
    if (lane == 63) wsum[wid] = incl;
    __syncthreads();
    int wpre = 0;
    for (int k = 0; k < wid; ++k) wpre += wsum[k];
    int ex = wpre + incl - v;
    if (i < n) {
        off[i] = ex;                         // local (no inter-block carry yet)
        dinv[i] = rsqrtf((float)v + 1.0f);   // +1 = self-loop
    }
    if (tid == 1023) btot[blockIdx.x] = ex + v;  // block total
}

__global__ __launch_bounds__(128) void k_scanB(const int* __restrict__ btot,
                                               int* __restrict__ bcar, int nb) {
    __shared__ int wsum[2];
    int tid = threadIdx.x, lane = tid & 63, wid = tid >> 6;
    int v = (tid < nb) ? btot[tid] : 0;
    int incl = v;
#pragma unroll
    for (int o = 1; o < 64; o <<= 1) {
        int t = __shfl_up(incl, o, 64);
        if (lane >= o) incl += t;
    }
    if (lane == 63) wsum[wid] = incl;
    __syncthreads();
    int wpre = (wid == 1) ? wsum[0] : 0;
    if (tid < nb) bcar[tid] = wpre + incl - v;
}

__global__ __launch_bounds__(1024) void k_scanC(int* __restrict__ off,
                                                const int* __restrict__ bcar,
                                                int* __restrict__ cur, int n, int E) {
    int i = blockIdx.x * 1024 + threadIdx.x;
    if (i < n) {
        int o = off[i] + bcar[blockIdx.x];
        off[i] = o;
        cur[i] = o;
    }
    if (i == 0) off[n] = E;
}

// -------------------------------- scatter src into CSR, XCD-affine ranges ---
// Block b: edge-chunk b>>3, dst-range b&7 (blocks round-robin across XCDs, so
// all writers of a CSR range share one L2). Batched iv4 loads give 8
// independent 16B loads in flight per thread (VGPR=4 scalar version was
// fully serialized -> latency-bound).
__global__ void k_scatter(const iv4* __restrict__ src4, const iv4* __restrict__ dst4,
                          const int* __restrict__ src, const int* __restrict__ dst,
                          int* __restrict__ cur, int* __restrict__ csr_src,
                          int E, int n) {
    int chunk = blockIdx.x >> 3;
    int range = blockIdx.x & (NXCD - 1);
    int rsz = (n + NXCD - 1) / NXCD;
    int lo = range * rsz;
    int hi = min(n, lo + rsz);
    int E4 = E >> 2;
    int base = chunk * 1024 + threadIdx.x;  // iv4 index; 256 threads * 4 batches

    iv4 dv[4], sv[4];
    bool ok[4];
#pragma unroll
    for (int i = 0; i < 4; ++i) {
        int j = base + i * 256;
        ok[i] = (j < E4);
        if (ok[i]) {
            dv[i] = __builtin_nontemporal_load(dst4 + j);
            sv[i] = __builtin_nontemporal_load(src4 + j);
        }
    }
#pragma unroll
    for (int i = 0; i < 4; ++i) {
        if (!ok[i]) continue;
        iv4 d = dv[i], s = sv[i];
        if (d.x >= lo && d.x < hi) { int p = atomicAdd(&cur[d.x], 1); csr_src[p] = s.x; }
        if (d.y >= lo && d.y < hi) { int p = atomicAdd(&cur[d.y], 1); csr_src[p] = s.y; }
        if (d.z >= lo && d.z < hi) { int p = atomicAdd(&cur[d.z], 1); csr_src[p] = s.z; }
        if (d.w >= lo && d.w < hi) { int p = atomicAdd(&cur[d.w], 1); csr_src[p] = s.w; }
    }
    if (chunk == 0) {  // scalar tail (E % 4 edges)
        for (int e = (E & ~3) + (int)threadIdx.x; e < E; e += 256) {
            int d = dst[e];
            if (d >= lo && d < hi) { int p = atomicAdd(&cur[d], 1); csr_src[p] = src[e]; }
        }
    }
}

// ------------------------------------------------------- layer 1: x @ W1 ----
// One thread per row; W indices wave-uniform -> scalar-pipe s_loads (the
// 4-lane split made W lane-dependent: 819M VMEM loads, 10x regression R6).
__global__ void k_gemm1(const float* __restrict__ x, const float* __restrict__ W,
                        float* __restrict__ h1, int n) {
    int row = blockIdx.x * blockDim.x + threadIdx.x;
    if (row >= n) return;
    const float4* xr = reinterpret_cast<const float4*>(x + (size_t)row * IN_FEAT);
    float acc[HID];
#pragma unroll
    for (int c = 0; c < HID; ++c) acc[c] = 0.0f;
#pragma unroll 2
    for (int kt = 0; kt < IN_FEAT / 4; ++kt) {
        float4 xv = xr[kt];
        const float* wk = W + (size_t)kt * 4 * HID;
#pragma unroll
        for (int c = 0; c < HID; ++c) acc[c] = fmaf(xv.x, wk[c], acc[c]);
#pragma unroll
        for (int c = 0; c < HID; ++c) acc[c] = fmaf(xv.y, wk[HID + c], acc[c]);
#pragma unroll
        for (int c = 0; c < HID; ++c) acc[c] = fmaf(xv.z, wk[2 * HID + c], acc[c]);
#pragma unroll
        for (int c = 0; c < HID; ++c) acc[c] = fmaf(xv.w, wk[3 * HID + c], acc[c]);
    }
    float4* hp = reinterpret_cast<float4*>(h1 + (size_t)row * HID);
#pragma unroll
    for (int j = 0; j < 4; ++j)
        hp[j] = make_float4(acc[4 * j], acc[4 * j + 1], acc[4 * j + 2], acc[4 * j + 3]);
}

// ------------------- gather layer 1 + bias + relu + @W2 (fused, 4 lanes/v) --
__global__ void k_gather1(const float* __restrict__ h1, const int* __restrict__ csr_src,
                          const int* __restrict__ off, const float* __restrict__ dinv,
                          const float* __restrict__ b1, const float* __restrict__ W2,
                          float* __restrict__ h2, int n) {
    int t = blockIdx.x * blockDim.x + threadIdx.x;
    int v = t >> 2, part = t & 3;
    if (v >= n) return;
    float di = dinv[v];
    float4 hv = reinterpret_cast<const float4*>(h1 + (size_t)v * HID)[part];
    float dw = di * di;
    float4 acc = make_float4(hv.x * dw, hv.y * dw, hv.z * dw, hv.w * dw);
    int beg = off[v], end = off[v + 1];
    for (int i = beg; i < end; ++i) {
        int s = csr_src[i];  // cached: consecutive iters reuse the line
        float w = dinv[s] * di;
        float4 hs = reinterpret_cast<const float4*>(h1 + (size_t)s * HID)[part];
        acc.x = fmaf(hs.x, w, acc.x);
        acc.y = fmaf(hs.y, w, acc.y);
        acc.z = fmaf(hs.z, w, acc.z);
        acc.w = fmaf(hs.w, w, acc.w);
    }
    float tt[4];
    tt[0] = fmaxf(acc.x + b1[part * 4 + 0], 0.0f);
    tt[1] = fmaxf(acc.y + b1[part * 4 + 1], 0.0f);
    tt[2] = fmaxf(acc.z + b1[part * 4 + 2], 0.0f);
    tt[3] = fmaxf(acc.w + b1[part * 4 + 3], 0.0f);
    float o[NC];
#pragma unroll
    for (int c = 0; c < NC; ++c) o[c] = 0.0f;
#pragma unroll
    for (int j = 0; j < 4; ++j) {
        int k = part * 4 + j;
#pragma unroll
        for (int c = 0; c < NC; ++c) o[c] = fmaf(tt[j], W2[k * NC + c], o[c]);
    }
#pragma unroll
    for (int c = 0; c < NC; ++c) {
        o[c] += __shfl_xor(o[c], 1);
        o[c] += __shfl_xor(o[c], 2);
    }
    float4* hp = reinterpret_cast<float4*>(h2 + (size_t)v * 8);
    if (part == 0) hp[0] = make_float4(o[0], o[1], o[2], o[3]);
    if (part == 1) hp[1] = make_float4(o[4], o[5], o[6], 0.0f);
}

// ------------------- gather layer 2 + bias + log_softmax (fused, 1 th/v) ----
__global__ void k_gather2(const float* __restrict__ h2, const int* __restrict__ csr_src,
                          const int* __restrict__ off, const float* __restrict__ dinv,
                          const float* __restrict__ b2, float* __restrict__ out, int n) {
    int v = blockIdx.x * blockDim.x + threadIdx.x;
    if (v >= n) return;
    float di = dinv[v];
    float dw = di * di;
    const float4* hr = reinterpret_cast<const float4*>(h2 + (size_t)v * 8);
    float4 s0 = hr[0], s1 = hr[1];
    float4 a0 = make_float4(s0.x * dw, s0.y * dw, s0.z * dw, s0.w * dw);
    float4 a1 = make_float4(s1.x * dw, s1.y * dw, s1.z * dw, 0.0f);
    int beg = off[v], end = off[v + 1];
    for (int i = beg; i < end; ++i) {
        int s = csr_src[i];  // cached
        float w = dinv[s] * di;
        const float4* hs = reinterpret_cast<const float4*>(h2 + (size_t)s * 8);
        float4 v0 = hs[0], v1 = hs[1];
        a0.x = fmaf(v0.x, w, a0.x);
        a0.y = fmaf(v0.y, w, a0.y);
        a0.z = fmaf(v0.z, w, a0.z);
        a0.w = fmaf(v0.w, w, a0.w);
        a1.x = fmaf(v1.x, w, a1.x);
        a1.y = fmaf(v1.y, w, a1.y);
        a1.z = fmaf(v1.z, w, a1.z);
    }
    float z[NC];
    z[0] = a0.x + b2[0]; z[1] = a0.y + b2[1]; z[2] = a0.z + b2[2]; z[3] = a0.w + b2[3];
    z[4] = a1.x + b2[4]; z[5] = a1.y + b2[5]; z[6] = a1.z + b2[6];
    float m = z[0];
#pragma unroll
    for (int c = 1; c < NC; ++c) m = fmaxf(m, z[c]);
    float sum = 0.0f;
#pragma unroll
    for (int c = 0; c < NC; ++c) sum += expf(z[c] - m);
    float lse = logf(sum) + m;
#pragma unroll
    for (int c = 0; c < NC; ++c) out[(size_t)v * NC + c] = z[c] - lse;
}

// -----------------------------------------------------------------------------
extern "C" void kernel_launch(void* const* d_in, const int* in_sizes, int n_in,
                              void* d_out, int out_size, void* d_ws, size_t ws_size,
                              hipStream_t stream) {
    const float* x  = (const float*)d_in[0];
    const int*   ei = (const int*)d_in[1];
    const float* W1 = (const float*)d_in[2];
    const float* b1 = (const float*)d_in[3];
    const float* W2 = (const float*)d_in[4];
    const float* b2 = (const float*)d_in[5];

    int n = in_sizes[0] / IN_FEAT;
    int E = in_sizes[1] / 2;
    const int* src = ei;
    const int* dst = ei + E;
    const iv4* src4 = (const iv4*)src;
    const iv4* dst4 = (const iv4*)dst;

    // workspace layout (16B-aligned chunks first)
    char* p = (char*)d_ws;
    float* h1      = (float*)p;                 p += (size_t)HID * n * sizeof(float); // 6.4 MB
    float* h2      = (float*)p;                 p += (size_t)8 * n * sizeof(float);   // 3.2 MB
    int*   csr_src = (int*)p;                   p += (size_t)E * sizeof(int);         // 12.8 MB
    int*   deg     = (int*)p;                   p += (size_t)n * sizeof(int);
    int*   off     = (int*)p;                   p += (size_t)(n + 1) * sizeof(int);
    int*   cur     = (int*)p;                   p += (size_t)n * sizeof(int);
    float* dinv    = (float*)p;                 p += (size_t)n * sizeof(float);
    int*   btot    = (int*)p;                   p += (size_t)128 * sizeof(int);
    int*   bcar    = (int*)p;                   p += (size_t)128 * sizeof(int);

    const int tb = 256;
    int E4 = E >> 2;
    int gE4 = (E4 + tb - 1) / tb;
    int gN = (n + tb - 1) / tb;
    int gN4 = (4 * n + tb - 1) / tb;
    int nb = (n + 1023) / 1024;                       // scan blocks (<=128)
    int nchunk = (E4 + 1023) / 1024;                  // scatter chunks (4096 edges each)

    hipMemsetAsync(deg, 0, (size_t)n * sizeof(int), stream);
    k_count  <<<gE4, tb, 0, stream>>>(dst4, dst, deg, E);
    k_scanA  <<<nb, 1024, 0, stream>>>(deg, off, dinv, btot, n);
    k_scanB  <<<1, 128, 0, stream>>>(btot, bcar, nb);
    k_scanC  <<<nb, 1024, 0, stream>>>(off, bcar, cur, n, E);
    k_scatter<<<nchunk * NXCD, tb, 0, stream>>>(src4, dst4, src, dst, cur, csr_src, E, n);
    k_gemm1  <<<gN,  tb, 0, stream>>>(x, W1, h1, n);
    k_gather1<<<gN4, tb, 0, stream>>>(h1, csr_src, off, dinv, b1, W2, h2, n);
    k_gather2<<<gN,  tb, 0, stream>>>(h2, csr_src, off, dinv, b2, (float*)d_out, n);
}